// Round 5
// baseline (553.070 us; speedup 1.0000x reference)
//
#include <hip/hip_runtime.h>
#include <hip/hip_bf16.h>
#include <hip/hip_fp16.h>
#include <math.h>

// Edge_Encoder_Residual: 2-layer GATv2 on line-graph + time-MLP + decoder.
// Round 5: bucket-granular CSR. Edges are scattered into 32-dst buckets
// (cap 768, mean 512) -> scatter writes stay in a ~200KB L2-resident window
// (was 6.4MB thrash, 105MB HBM writes). Exact per-dst lists are recovered
// inside the GAT kernel with a 32-bin LDS counting sort (one 64-thr block
// per bucket). Replaces k_hist/k_base/k_scatter with one k_bucket pass.

#define BLK 256
#define BDST 32          // dsts per bucket
#define CAP 768          // edges capacity per bucket (mean 512, P(overflow)~1e-24)

typedef _Float16 half4v __attribute__((ext_vector_type(4)));

__device__ __forceinline__ float leaky02(float x) { return x >= 0.f ? x : 0.2f * x; }
__device__ __forceinline__ float relu(float x) { return x > 0.f ? x : 0.f; }

// ---------- tiny: time embedding + MLP + collapsed decoder matrices ----------
__global__ void k_tiny(const int* __restrict__ t,
                       const float* __restrict__ Wt0, const float* __restrict__ bt0,
                       const float* __restrict__ Wt1, const float* __restrict__ bt1,
                       const float* __restrict__ Wfd, const float* __restrict__ bfd,
                       const float* __restrict__ Wcls, const float* __restrict__ bcls,
                       float* __restrict__ wcomb,   // [96][2]
                       float* __restrict__ bfinal)  // [2]
{
    __shared__ float temb[16];
    int tid = threadIdx.x;
    if (tid == 0) {
        float tf = (float)t[0];  // * (1000/MAX_TIME) == *1
        float e0[16], v1[16];
        const float cexp = -logf(10000.f) / 7.f;
        for (int j = 0; j < 8; ++j) {
            float ang = tf * expf((float)j * cexp);
            e0[j] = sinf(ang);
            e0[8 + j] = cosf(ang);
        }
        for (int i = 0; i < 16; ++i) {
            float a = bt0[i];
            for (int j = 0; j < 16; ++j) a += e0[j] * Wt0[j * 16 + i];
            v1[i] = a / (1.f + expf(-a));  // silu
        }
        for (int i = 0; i < 16; ++i) {
            float a = bt1[i];
            for (int j = 0; j < 16; ++j) a += v1[j] * Wt1[j * 16 + i];
            temb[i] = a / (1.f + expf(-a));
        }
    }
    __syncthreads();
    if (tid < 192) {  // wcomb[i][k] = sum_j Wfd[i][j] * Wcls[j][k]
        int i = tid >> 1, k = tid & 1;
        float a = 0.f;
        for (int j = 0; j < 32; ++j) a += Wfd[i * 32 + j] * Wcls[j * 2 + k];
        wcomb[tid] = a;
    }
    __syncthreads();
    if (tid < 2) {  // bias + time contribution (node-constant)
        float a = bcls[tid];
        for (int j = 0; j < 32; ++j) a += bfd[j] * Wcls[j * 2 + tid];
        for (int d = 0; d < 16; ++d) a += temb[d] * wcomb[(64 + d) * 2 + tid];
        bfinal[tid] = a;
    }
}

// ---------- bucket scatter ----------
__global__ void k_zero2(int* __restrict__ cur, int NB)
{
    int gid = blockIdx.x * BLK + threadIdx.x;
    if (gid < NB) cur[gid] = 0;
}

__global__ void k_bucket(const int* __restrict__ ei, int E,
                         int* __restrict__ cur, int* __restrict__ tmp)
{
    int e = blockIdx.x * BLK + threadIdx.x;
    if (e >= E) return;
    int s = ei[e];
    int d = ei[E + e];
    int b = d >> 5;
    int p = atomicAdd(&cur[b], 1);
    if (p < CAP) tmp[(size_t)b * CAP + p] = (s << 5) | (d & 31);
}

// ---------- layer 0 node precompute: 8 nodes per wave, lane = channel ----------
__global__ void k_pre0v(const float* __restrict__ x,
                        const float* __restrict__ Wl, const float* __restrict__ bl,
                        const float* __restrict__ Wr, const float* __restrict__ br,
                        const float* __restrict__ Wres, const float* __restrict__ bres,
                        _Float16* __restrict__ xlh, float* __restrict__ xr, float* __restrict__ res,
                        int N)
{
    int wid = (int)(((long long)blockIdx.x * BLK + threadIdx.x) >> 6);
    int c = threadIdx.x & 63;
    int n0 = wid * 8;
    if (n0 >= N) return;
    int ra_n = n0 + (c >> 4);     if (ra_n >= N) ra_n = N - 1;
    int rb_n = n0 + 4 + (c >> 4); if (rb_n >= N) rb_n = N - 1;
    float ra = x[(size_t)ra_n * 16 + (c & 15)];
    float rb = x[(size_t)rb_n * 16 + (c & 15)];

    float al[8], ar[8], as[8];
    float vbl = bl[c], vbr = br[c], vbs = bres[c];
    #pragma unroll
    for (int i = 0; i < 8; ++i) { al[i] = vbl; ar[i] = vbr; as[i] = vbs; }
    #pragma unroll
    for (int k = 0; k < 16; ++k) {
        float wl = Wl[k * 64 + c], wr_ = Wr[k * 64 + c], ws = Wres[k * 64 + c];
        #pragma unroll
        for (int i = 0; i < 8; ++i) {
            float hv = __shfl(i < 4 ? ra : rb, ((i & 3) << 4) | k, 64);
            al[i] = fmaf(hv, wl, al[i]);
            ar[i] = fmaf(hv, wr_, ar[i]);
            as[i] = fmaf(hv, ws, as[i]);
        }
    }
    #pragma unroll
    for (int i = 0; i < 8; ++i) {
        int n = n0 + i;
        if (n < N) {
            xlh[(size_t)n * 64 + c] = (_Float16)al[i];
            xr[(size_t)n * 64 + c]  = ar[i];
            res[(size_t)n * 64 + c] = relu(as[i]);
        }
    }
}

// ---------- layer 1 node precompute: 8 nodes per wave ----------
__global__ void k_pre1v(const float* __restrict__ h,
                        const float* __restrict__ Wl, const float* __restrict__ Wr,
                        const float* __restrict__ Wres, const float* __restrict__ bres,
                        _Float16* __restrict__ xlh, float* __restrict__ xr, float* __restrict__ res,
                        int N)
{
    int wid = (int)(((long long)blockIdx.x * BLK + threadIdx.x) >> 6);
    int c = threadIdx.x & 63;
    int n0 = wid * 8;
    if (n0 >= N) return;
    float hreg[8];
    #pragma unroll
    for (int i = 0; i < 8; ++i) {
        int n = n0 + i; if (n >= N) n = N - 1;
        hreg[i] = h[(size_t)n * 64 + c];
    }
    float al[8], ar[8], as[8];
    float vbs = bres[c];
    #pragma unroll
    for (int i = 0; i < 8; ++i) { al[i] = 0.f; ar[i] = 0.f; as[i] = vbs; }
    #pragma unroll 4
    for (int k = 0; k < 64; ++k) {
        float wl = Wl[k * 64 + c], wr_ = Wr[k * 64 + c], ws = Wres[k * 64 + c];
        #pragma unroll
        for (int i = 0; i < 8; ++i) {
            float hv = __shfl(hreg[i], k, 64);
            al[i] = fmaf(hv, wl, al[i]);
            ar[i] = fmaf(hv, wr_, ar[i]);
            as[i] = fmaf(hv, ws, as[i]);
        }
    }
    #pragma unroll
    for (int i = 0; i < 8; ++i) {
        int n = n0 + i;
        if (n < N) {
            xlh[(size_t)n * 64 + c] = (_Float16)al[i];
            xr[(size_t)n * 64 + c]  = ar[i];
            res[(size_t)n * 64 + c] = relu(as[i]);
        }
    }
}

// ---------- fused GATv2 aggregation: one 64-thr block per 32-dst bucket ----------
// LDS counting sort (32 bins) recovers exact per-dst src lists from the
// bucket's packed tags, then the wave processes 4 dsts at a time
// (16 lanes/dst, 4 ch/lane; q 0-7 head 0, q 8-15 head 1), online softmax.
template <bool DEC>
__global__ void k_gat2v2(const int* __restrict__ cur, const int* __restrict__ tmp,
                         const _Float16* __restrict__ xlh, const float* __restrict__ xr,
                         const float* __restrict__ att, const float* __restrict__ bias,
                         const float* __restrict__ res,
                         float* __restrict__ hout,
                         const float* __restrict__ cond, const float* __restrict__ wcomb,
                         const float* __restrict__ bfinal, float* __restrict__ out,
                         int N)
{
    __shared__ int lh[BDST];
    __shared__ int rp[BDST + 1];
    __shared__ int cc[BDST];
    __shared__ int tags[CAP];

    int b = blockIdx.x;
    int tid = threadIdx.x;
    int nE = cur[b]; if (nE > CAP) nE = CAP;
    const int* bucket = tmp + (size_t)b * CAP;

    if (tid < BDST) lh[tid] = 0;
    __syncthreads();
    for (int k = tid; k < nE; k += 64) atomicAdd(&lh[bucket[k] & 31], 1);
    __syncthreads();
    if (tid == 0) {
        int acc = 0;
        rp[0] = 0;
        #pragma unroll
        for (int i = 0; i < BDST; ++i) { acc += lh[i]; rp[i + 1] = acc; }
    }
    __syncthreads();
    if (tid < BDST) cc[tid] = rp[tid];
    __syncthreads();
    for (int k = tid; k < nE; k += 64) {
        int tg = bucket[k];
        int r = atomicAdd(&cc[tg & 31], 1);
        tags[r] = tg >> 5;
    }
    __syncthreads();

    int g = tid >> 4, q = tid & 15;
    float4 a4 = *(const float4*)(att + q * 4);

    #pragma unroll
    for (int rep = 0; rep < 8; ++rep) {
        int dlow = rep * 4 + g;
        int node = b * BDST + dlow;
        bool nvalid = node < N;
        int n = nvalid ? node : 0;

        float4 xr4 = *(const float4*)(xr + (size_t)n * 64 + q * 4);
        half4v hs = *(const half4v*)(xlh + (size_t)n * 64 + q * 4);
        float s0 = (float)hs.x, s1 = (float)hs.y, s2 = (float)hs.z, s3 = (float)hs.w;
        float lv = leaky02(s0 + xr4.x) * a4.x + leaky02(s1 + xr4.y) * a4.y
                 + leaky02(s2 + xr4.z) * a4.z + leaky02(s3 + xr4.w) * a4.w;
        lv += __shfl_xor(lv, 1, 8);
        lv += __shfl_xor(lv, 2, 8);
        lv += __shfl_xor(lv, 4, 8);

        float m = lv, den = 1.f;
        float ac0 = s0, ac1 = s1, ac2 = s2, ac3 = s3;

        int deg = nvalid ? (rp[dlow + 1] - rp[dlow]) : 0;
        int base = rp[dlow];

        int t1 = max(deg, __shfl_xor(deg, 16, 64));
        int wavemax = max(t1, __shfl_xor(t1, 32, 64));

        int s_nxt = (deg > 0) ? tags[base] : n;
        half4v h_nxt = *(const half4v*)(xlh + (size_t)s_nxt * 64 + q * 4);

        for (int j = 0; j < wavemax; ++j) {
            bool act = j < deg;
            half4v hx = h_nxt;
            int nxt = (j + 1 < deg) ? tags[base + j + 1] : n;
            h_nxt = *(const half4v*)(xlh + (size_t)nxt * 64 + q * 4);

            float x0 = (float)hx.x, x1 = (float)hx.y, x2 = (float)hx.z, x3 = (float)hx.w;
            float e = leaky02(x0 + xr4.x) * a4.x + leaky02(x1 + xr4.y) * a4.y
                    + leaky02(x2 + xr4.z) * a4.z + leaky02(x3 + xr4.w) * a4.w;
            e += __shfl_xor(e, 1, 8);
            e += __shfl_xor(e, 2, 8);
            e += __shfl_xor(e, 4, 8);
            if (!act) e = -1e30f;
            float mn = fmaxf(m, e);
            float sc = __expf(m - mn);
            float ex = __expf(e - mn);
            den = den * sc + ex;
            ac0 = ac0 * sc + ex * x0;
            ac1 = ac1 * sc + ex * x1;
            ac2 = ac2 * sc + ex * x2;
            ac3 = ac3 * sc + ex * x3;
            m = mn;
        }

        float inv = 1.f / den;
        float4 r4 = *(const float4*)(res + (size_t)n * 64 + q * 4);
        float h0, h1, h2, h3;
        if (bias) {
            const float4 b4 = *(const float4*)(bias + q * 4);
            h0 = relu(ac0 * inv + b4.x) + r4.x;
            h1 = relu(ac1 * inv + b4.y) + r4.y;
            h2 = relu(ac2 * inv + b4.z) + r4.z;
            h3 = relu(ac3 * inv + b4.w) + r4.w;
        } else {
            h0 = relu(ac0 * inv) + r4.x;
            h1 = relu(ac1 * inv) + r4.y;
            h2 = relu(ac2 * inv) + r4.z;
            h3 = relu(ac3 * inv) + r4.w;
        }

        if (!DEC) {
            if (nvalid) {
                float4 o; o.x = h0; o.y = h1; o.z = h2; o.w = h3;
                *(float4*)(hout + (size_t)n * 64 + q * 4) = o;
            }
        } else {
            int c0 = q * 4;
            float p0 = h0 * wcomb[(c0 + 0) * 2] + h1 * wcomb[(c0 + 1) * 2]
                     + h2 * wcomb[(c0 + 2) * 2] + h3 * wcomb[(c0 + 3) * 2];
            float p1 = h0 * wcomb[(c0 + 0) * 2 + 1] + h1 * wcomb[(c0 + 1) * 2 + 1]
                     + h2 * wcomb[(c0 + 2) * 2 + 1] + h3 * wcomb[(c0 + 3) * 2 + 1];
            if (q < 4) {
                float4 c4 = *(const float4*)(cond + (size_t)n * 16 + q * 4);
                int d0 = 80 + q * 4;
                p0 += c4.x * wcomb[(d0 + 0) * 2] + c4.y * wcomb[(d0 + 1) * 2]
                    + c4.z * wcomb[(d0 + 2) * 2] + c4.w * wcomb[(d0 + 3) * 2];
                p1 += c4.x * wcomb[(d0 + 0) * 2 + 1] + c4.y * wcomb[(d0 + 1) * 2 + 1]
                    + c4.z * wcomb[(d0 + 2) * 2 + 1] + c4.w * wcomb[(d0 + 3) * 2 + 1];
            }
            #pragma unroll
            for (int off = 1; off < 16; off <<= 1) {
                p0 += __shfl_xor(p0, off, 16);
                p1 += __shfl_xor(p1, off, 16);
            }
            if (q == 0 && nvalid) {
                out[(size_t)n * 2] = p0 + bfinal[0];
                out[(size_t)n * 2 + 1] = p1 + bfinal[1];
            }
        }
    }
}

static inline int gblk(long long threads) { return (int)((threads + BLK - 1) / BLK); }

extern "C" void kernel_launch(void* const* d_in, const int* in_sizes, int n_in,
                              void* d_out, int out_size, void* d_ws, size_t ws_size,
                              hipStream_t stream) {
    const float* x     = (const float*)d_in[0];
    const int*   ei    = (const int*)d_in[1];
    const int*   t     = (const int*)d_in[2];
    const float* cond  = (const float*)d_in[3];
    const float* Wl0   = (const float*)d_in[4];
    const float* bl0   = (const float*)d_in[5];
    const float* Wr0   = (const float*)d_in[6];
    const float* br0   = (const float*)d_in[7];
    const float* att0  = (const float*)d_in[8];
    const float* bias0 = (const float*)d_in[9];
    const float* Wres0 = (const float*)d_in[10];
    const float* bres0 = (const float*)d_in[11];
    const float* Wl1   = (const float*)d_in[12];
    const float* Wr1   = (const float*)d_in[13];
    const float* att1  = (const float*)d_in[14];
    const float* Wres1 = (const float*)d_in[15];
    const float* bres1 = (const float*)d_in[16];
    const float* Wt0   = (const float*)d_in[17];
    const float* bt0   = (const float*)d_in[18];
    const float* Wt1   = (const float*)d_in[19];
    const float* bt1   = (const float*)d_in[20];
    const float* Wfd   = (const float*)d_in[21];
    const float* bfd   = (const float*)d_in[22];
    const float* Wcls  = (const float*)d_in[23];
    const float* bcls  = (const float*)d_in[24];
    float* out = (float*)d_out;

    const int N  = in_sizes[0] / 16;
    const int E  = in_sizes[1] / 2;
    const int NB = (N + BDST - 1) / BDST;

    float* ws = (float*)d_ws;
    size_t o = 0;
    float* xr    = ws + o; o += (size_t)N * 64;
    float* res   = ws + o; o += (size_t)N * 64;
    float* hbuf  = ws + o; o += (size_t)N * 64;
    _Float16* xlh = (_Float16*)(ws + o); o += (size_t)N * 32;  // 16B-aligned
    float* wcomb = ws + o; o += 192;
    float* bfin  = ws + o; o += 2;
    int* iws     = (int*)(ws + o);
    size_t io = 0;
    int* cur    = iws + io; io += NB;
    int* tmp    = iws + io; io += (size_t)NB * CAP;

    // tiny decoder/time precompute
    k_tiny<<<1, BLK, 0, stream>>>(t, Wt0, bt0, Wt1, bt1, Wfd, bfd, Wcls, bcls, wcomb, bfin);

    // ---- bucket CSR build ----
    k_zero2<<<gblk(NB), BLK, 0, stream>>>(cur, NB);
    k_bucket<<<gblk(E), BLK, 0, stream>>>(ei, E, cur, tmp);

    const long long preThreads = (long long)((N + 7) / 8) * 64;

    // ---- layer 0 ----
    k_pre0v<<<gblk(preThreads), BLK, 0, stream>>>(x, Wl0, bl0, Wr0, br0, Wres0, bres0, xlh, xr, res, N);
    k_gat2v2<false><<<NB, 64, 0, stream>>>(cur, tmp, xlh, xr, att0, bias0, res,
                                           hbuf, nullptr, nullptr, nullptr, nullptr, N);

    // ---- layer 1 (decoder fused) ----
    k_pre1v<<<gblk(preThreads), BLK, 0, stream>>>(hbuf, Wl1, Wr1, Wres1, bres1, xlh, xr, res, N);
    k_gat2v2<true><<<NB, 64, 0, stream>>>(cur, tmp, xlh, xr, att1, nullptr, res,
                                          nullptr, cond, wcomb, bfin, out, N);
}

// Round 6
// 387.298 us; speedup vs baseline: 1.4280x; 1.4280x over previous
//
#include <hip/hip_runtime.h>
#include <hip/hip_bf16.h>
#include <hip/hip_fp16.h>
#include <math.h>

// Edge_Encoder_Residual: 2-layer GATv2 on line-graph + time-MLP + decoder.
// Round 6: hierarchical radix partition of edges by dst.
//   histc (coarse 256-dst bins, LDS-agg, fire-forget) -> scan -> part
//   (block-agg cursor grabs: ~391 returning atomics per 4096 edges, 10x
//   fewer than per-edge) -> refine (deterministic, 0 returning atomics,
//   exact 32-dst fine segments). Evidence: per-edge atomic-WITH-RETURN
//   runs at 11 Gop/s vs 235 Gop/s fire-and-forget (r4/r5 vs r1 counters).
// GAT: 256-thr block per fine bucket (4 waves), exact segments, LDS
// counting sort, online softmax, 4 dsts/wave/rep, fused decoder in layer 1.

#define BLK 256
#define BDST 32            // dsts per fine bucket
#define CDST 256           // dsts per coarse bucket
#define CHUNK 4096         // edges per k_part block
#define FCAP 768           // LDS tag capacity per fine bucket (mean 512)
#define NBC_MAX 512        // max coarse buckets (N <= 131072, s fits 17 bits)

typedef _Float16 half4v __attribute__((ext_vector_type(4)));

__device__ __forceinline__ float leaky02(float x) { return x >= 0.f ? x : 0.2f * x; }
__device__ __forceinline__ float relu(float x) { return x > 0.f ? x : 0.f; }

// ---------- tiny: time embedding + MLP + collapsed decoder matrices ----------
__global__ void k_tiny(const int* __restrict__ t,
                       const float* __restrict__ Wt0, const float* __restrict__ bt0,
                       const float* __restrict__ Wt1, const float* __restrict__ bt1,
                       const float* __restrict__ Wfd, const float* __restrict__ bfd,
                       const float* __restrict__ Wcls, const float* __restrict__ bcls,
                       float* __restrict__ wcomb,   // [96][2]
                       float* __restrict__ bfinal)  // [2]
{
    __shared__ float temb[16];
    int tid = threadIdx.x;
    if (tid == 0) {
        float tf = (float)t[0];
        float e0[16], v1[16];
        const float cexp = -logf(10000.f) / 7.f;
        for (int j = 0; j < 8; ++j) {
            float ang = tf * expf((float)j * cexp);
            e0[j] = sinf(ang);
            e0[8 + j] = cosf(ang);
        }
        for (int i = 0; i < 16; ++i) {
            float a = bt0[i];
            for (int j = 0; j < 16; ++j) a += e0[j] * Wt0[j * 16 + i];
            v1[i] = a / (1.f + expf(-a));
        }
        for (int i = 0; i < 16; ++i) {
            float a = bt1[i];
            for (int j = 0; j < 16; ++j) a += v1[j] * Wt1[j * 16 + i];
            temb[i] = a / (1.f + expf(-a));
        }
    }
    __syncthreads();
    if (tid < 192) {
        int i = tid >> 1, k = tid & 1;
        float a = 0.f;
        for (int j = 0; j < 32; ++j) a += Wfd[i * 32 + j] * Wcls[j * 2 + k];
        wcomb[tid] = a;
    }
    __syncthreads();
    if (tid < 2) {
        float a = bcls[tid];
        for (int j = 0; j < 32; ++j) a += bfd[j] * Wcls[j * 2 + tid];
        for (int d = 0; d < 16; ++d) a += temb[d] * wcomb[(64 + d) * 2 + tid];
        bfinal[tid] = a;
    }
}

// ---------- radix pipeline ----------
__global__ void k_zeroc(int* __restrict__ ccnt, int NBC)
{
    int gid = blockIdx.x * BLK + threadIdx.x;
    if (gid < NBC) ccnt[gid] = 0;
}

// coarse histogram, LDS-aggregated, fire-and-forget global flush
__global__ void k_histc(const int* __restrict__ ei, int E, int NBC,
                        int* __restrict__ ccnt)
{
    __shared__ int h[NBC_MAX];
    int tid = threadIdx.x;
    for (int i = tid; i < NBC; i += BLK) h[i] = 0;
    __syncthreads();
    int e0 = blockIdx.x * CHUNK;
    #pragma unroll
    for (int k = 0; k < CHUNK / BLK; ++k) {
        int e = e0 + tid + k * BLK;
        if (e < E) atomicAdd(&h[ei[E + e] >> 8], 1);
    }
    __syncthreads();
    for (int i = tid; i < NBC; i += BLK) {
        int v = h[i];
        if (v) atomicAdd(&ccnt[i], v);   // no return use -> pipelines
    }
}

// exclusive prefix over coarse counts; init cursors
__global__ void k_scan(const int* __restrict__ ccnt, int NBC, int E,
                       int* __restrict__ cbase, int* __restrict__ ccur)
{
    if (threadIdx.x == 0) {
        int acc = 0;
        for (int i = 0; i < NBC; ++i) {
            cbase[i] = acc;
            acc += ccnt[i];
        }
        cbase[NBC] = acc;  // == E
    }
    __syncthreads();
    for (int i = threadIdx.x; i < NBC; i += BLK) ccur[i] = cbase[i];
}

// partition edges into coarse segments: tag = (s<<8) | (d & 255)
__global__ void k_part(const int* __restrict__ ei, int E, int NBC,
                       int* __restrict__ ccur, int* __restrict__ part)
{
    __shared__ int h[NBC_MAX];
    __shared__ int gb[NBC_MAX];
    int tid = threadIdx.x;
    int e0 = blockIdx.x * CHUNK;
    for (int i = tid; i < NBC; i += BLK) h[i] = 0;
    __syncthreads();
    int sv[CHUNK / BLK], dv[CHUNK / BLK];
    #pragma unroll
    for (int k = 0; k < CHUNK / BLK; ++k) {
        int e = e0 + tid + k * BLK;
        if (e < E) {
            sv[k] = ei[e];
            dv[k] = ei[E + e];
            atomicAdd(&h[dv[k] >> 8], 1);
        } else dv[k] = -1;
    }
    __syncthreads();
    for (int i = tid; i < NBC; i += BLK) {
        int v = h[i];
        gb[i] = v ? atomicAdd(&ccur[i], v) : 0;   // ~NBC returning atomics per block
    }
    __syncthreads();
    for (int i = tid; i < NBC; i += BLK) h[i] = gb[i];  // h becomes running cursor
    __syncthreads();
    #pragma unroll
    for (int k = 0; k < CHUNK / BLK; ++k) {
        if (dv[k] >= 0) {
            int p = atomicAdd(&h[dv[k] >> 8], 1);       // LDS atomic (fast)
            part[p] = (sv[k] << 8) | (dv[k] & 255);
        }
    }
}

// refine each coarse segment into 8 fine (32-dst) segments; deterministic.
// srcs tag = (s<<5) | (d & 31); fbeg/fend per fine bucket.
__global__ void k_refine(const int* __restrict__ cbase, const int* __restrict__ part,
                         int NBF, int* __restrict__ fbeg, int* __restrict__ fend,
                         int* __restrict__ srcs)
{
    __shared__ int fcnt[8];
    __shared__ int fcur[8];
    int b = blockIdx.x, tid = threadIdx.x;
    int beg = cbase[b], end = cbase[b + 1];
    if (tid < 8) fcnt[tid] = 0;
    __syncthreads();
    for (int k = beg + tid; k < end; k += BLK)
        atomicAdd(&fcnt[(part[k] >> 5) & 7], 1);
    __syncthreads();
    if (tid == 0) {
        int acc = beg;
        #pragma unroll
        for (int f = 0; f < 8; ++f) {
            int fb = b * 8 + f;
            fcur[f] = acc;
            if (fb < NBF) { fbeg[fb] = acc; acc += fcnt[f]; fend[fb] = acc; }
        }
    }
    __syncthreads();
    for (int k = beg + tid; k < end; k += BLK) {
        int tg = part[k];
        int p = atomicAdd(&fcur[(tg >> 5) & 7], 1);     // LDS atomic
        srcs[p] = ((tg >> 8) << 5) | (tg & 31);
    }
}

// ---------- layer 0 node precompute: 8 nodes per wave, lane = channel ----------
__global__ void k_pre0v(const float* __restrict__ x,
                        const float* __restrict__ Wl, const float* __restrict__ bl,
                        const float* __restrict__ Wr, const float* __restrict__ br,
                        const float* __restrict__ Wres, const float* __restrict__ bres,
                        _Float16* __restrict__ xlh, float* __restrict__ xr, float* __restrict__ res,
                        int N)
{
    int wid = (int)(((long long)blockIdx.x * BLK + threadIdx.x) >> 6);
    int c = threadIdx.x & 63;
    int n0 = wid * 8;
    if (n0 >= N) return;
    int ra_n = n0 + (c >> 4);     if (ra_n >= N) ra_n = N - 1;
    int rb_n = n0 + 4 + (c >> 4); if (rb_n >= N) rb_n = N - 1;
    float ra = x[(size_t)ra_n * 16 + (c & 15)];
    float rb = x[(size_t)rb_n * 16 + (c & 15)];

    float al[8], ar[8], as[8];
    float vbl = bl[c], vbr = br[c], vbs = bres[c];
    #pragma unroll
    for (int i = 0; i < 8; ++i) { al[i] = vbl; ar[i] = vbr; as[i] = vbs; }
    #pragma unroll
    for (int k = 0; k < 16; ++k) {
        float wl = Wl[k * 64 + c], wr_ = Wr[k * 64 + c], ws = Wres[k * 64 + c];
        #pragma unroll
        for (int i = 0; i < 8; ++i) {
            float hv = __shfl(i < 4 ? ra : rb, ((i & 3) << 4) | k, 64);
            al[i] = fmaf(hv, wl, al[i]);
            ar[i] = fmaf(hv, wr_, ar[i]);
            as[i] = fmaf(hv, ws, as[i]);
        }
    }
    #pragma unroll
    for (int i = 0; i < 8; ++i) {
        int n = n0 + i;
        if (n < N) {
            xlh[(size_t)n * 64 + c] = (_Float16)al[i];
            xr[(size_t)n * 64 + c]  = ar[i];
            res[(size_t)n * 64 + c] = relu(as[i]);
        }
    }
}

// ---------- layer 1 node precompute: 8 nodes per wave ----------
__global__ void k_pre1v(const float* __restrict__ h,
                        const float* __restrict__ Wl, const float* __restrict__ Wr,
                        const float* __restrict__ Wres, const float* __restrict__ bres,
                        _Float16* __restrict__ xlh, float* __restrict__ xr, float* __restrict__ res,
                        int N)
{
    int wid = (int)(((long long)blockIdx.x * BLK + threadIdx.x) >> 6);
    int c = threadIdx.x & 63;
    int n0 = wid * 8;
    if (n0 >= N) return;
    float hreg[8];
    #pragma unroll
    for (int i = 0; i < 8; ++i) {
        int n = n0 + i; if (n >= N) n = N - 1;
        hreg[i] = h[(size_t)n * 64 + c];
    }
    float al[8], ar[8], as[8];
    float vbs = bres[c];
    #pragma unroll
    for (int i = 0; i < 8; ++i) { al[i] = 0.f; ar[i] = 0.f; as[i] = vbs; }
    #pragma unroll 4
    for (int k = 0; k < 64; ++k) {
        float wl = Wl[k * 64 + c], wr_ = Wr[k * 64 + c], ws = Wres[k * 64 + c];
        #pragma unroll
        for (int i = 0; i < 8; ++i) {
            float hv = __shfl(hreg[i], k, 64);
            al[i] = fmaf(hv, wl, al[i]);
            ar[i] = fmaf(hv, wr_, ar[i]);
            as[i] = fmaf(hv, ws, as[i]);
        }
    }
    #pragma unroll
    for (int i = 0; i < 8; ++i) {
        int n = n0 + i;
        if (n < N) {
            xlh[(size_t)n * 64 + c] = (_Float16)al[i];
            xr[(size_t)n * 64 + c]  = ar[i];
            res[(size_t)n * 64 + c] = relu(as[i]);
        }
    }
}

// ---------- fused GATv2: one 256-thr block (4 waves) per 32-dst fine bucket ----
// LDS counting sort recovers per-dst lists; wave w handles dsts w*8..w*8+7
// in 2 reps of 4 (16 lanes/dst, 4 ch/lane; q 0-7 head 0, q 8-15 head 1).
template <bool DEC>
__global__ void k_gat3(const int* __restrict__ fbeg, const int* __restrict__ fend,
                       const int* __restrict__ srcs,
                       const _Float16* __restrict__ xlh, const float* __restrict__ xr,
                       const float* __restrict__ att, const float* __restrict__ bias,
                       const float* __restrict__ res,
                       float* __restrict__ hout,
                       const float* __restrict__ cond, const float* __restrict__ wcomb,
                       const float* __restrict__ bfinal, float* __restrict__ out,
                       int N)
{
    __shared__ int lh[BDST];
    __shared__ int rp[BDST + 1];
    __shared__ int cc[BDST];
    __shared__ int tags[FCAP];

    int b = blockIdx.x;
    int tid = threadIdx.x;
    int beg = fbeg[b];
    int nE = fend[b] - beg; if (nE > FCAP) nE = FCAP;

    if (tid < BDST) lh[tid] = 0;
    __syncthreads();
    for (int k = tid; k < nE; k += BLK) atomicAdd(&lh[srcs[beg + k] & 31], 1);
    __syncthreads();
    if (tid == 0) {
        int acc = 0;
        rp[0] = 0;
        #pragma unroll
        for (int i = 0; i < BDST; ++i) { acc += lh[i]; rp[i + 1] = acc; }
    }
    __syncthreads();
    if (tid < BDST) cc[tid] = rp[tid];
    __syncthreads();
    for (int k = tid; k < nE; k += BLK) {
        int tg = srcs[beg + k];
        int r = atomicAdd(&cc[tg & 31], 1);
        tags[r] = tg >> 5;
    }
    __syncthreads();

    int lane = tid & 63, w = tid >> 6;
    int g = lane >> 4, q = lane & 15;
    float4 a4 = *(const float4*)(att + q * 4);

    #pragma unroll
    for (int rep = 0; rep < 2; ++rep) {
        int dlow = w * 8 + rep * 4 + g;
        int node = b * BDST + dlow;
        bool nvalid = node < N;
        int n = nvalid ? node : 0;

        float4 xr4 = *(const float4*)(xr + (size_t)n * 64 + q * 4);
        half4v hs = *(const half4v*)(xlh + (size_t)n * 64 + q * 4);
        float s0 = (float)hs.x, s1 = (float)hs.y, s2 = (float)hs.z, s3 = (float)hs.w;
        float lv = leaky02(s0 + xr4.x) * a4.x + leaky02(s1 + xr4.y) * a4.y
                 + leaky02(s2 + xr4.z) * a4.z + leaky02(s3 + xr4.w) * a4.w;
        lv += __shfl_xor(lv, 1, 8);
        lv += __shfl_xor(lv, 2, 8);
        lv += __shfl_xor(lv, 4, 8);

        float m = lv, den = 1.f;
        float ac0 = s0, ac1 = s1, ac2 = s2, ac3 = s3;

        int deg = nvalid ? (rp[dlow + 1] - rp[dlow]) : 0;
        int base = nvalid ? rp[dlow] : 0;

        int t1 = max(deg, __shfl_xor(deg, 16, 64));
        int wavemax = max(t1, __shfl_xor(t1, 32, 64));

        int s_nxt = (deg > 0) ? tags[base] : n;
        half4v h_nxt = *(const half4v*)(xlh + (size_t)s_nxt * 64 + q * 4);

        for (int j = 0; j < wavemax; ++j) {
            bool act = j < deg;
            half4v hx = h_nxt;
            int nxt = (j + 1 < deg) ? tags[base + j + 1] : n;
            h_nxt = *(const half4v*)(xlh + (size_t)nxt * 64 + q * 4);

            float x0 = (float)hx.x, x1 = (float)hx.y, x2 = (float)hx.z, x3 = (float)hx.w;
            float e = leaky02(x0 + xr4.x) * a4.x + leaky02(x1 + xr4.y) * a4.y
                    + leaky02(x2 + xr4.z) * a4.z + leaky02(x3 + xr4.w) * a4.w;
            e += __shfl_xor(e, 1, 8);
            e += __shfl_xor(e, 2, 8);
            e += __shfl_xor(e, 4, 8);
            if (!act) e = -1e30f;
            float mn = fmaxf(m, e);
            float sc = __expf(m - mn);
            float ex = __expf(e - mn);
            den = den * sc + ex;
            ac0 = ac0 * sc + ex * x0;
            ac1 = ac1 * sc + ex * x1;
            ac2 = ac2 * sc + ex * x2;
            ac3 = ac3 * sc + ex * x3;
            m = mn;
        }

        float inv = 1.f / den;
        float4 r4 = *(const float4*)(res + (size_t)n * 64 + q * 4);
        float h0, h1, h2, h3;
        if (bias) {
            const float4 b4 = *(const float4*)(bias + q * 4);
            h0 = relu(ac0 * inv + b4.x) + r4.x;
            h1 = relu(ac1 * inv + b4.y) + r4.y;
            h2 = relu(ac2 * inv + b4.z) + r4.z;
            h3 = relu(ac3 * inv + b4.w) + r4.w;
        } else {
            h0 = relu(ac0 * inv) + r4.x;
            h1 = relu(ac1 * inv) + r4.y;
            h2 = relu(ac2 * inv) + r4.z;
            h3 = relu(ac3 * inv) + r4.w;
        }

        if (!DEC) {
            if (nvalid) {
                float4 o; o.x = h0; o.y = h1; o.z = h2; o.w = h3;
                *(float4*)(hout + (size_t)n * 64 + q * 4) = o;
            }
        } else {
            int c0 = q * 4;
            float p0 = h0 * wcomb[(c0 + 0) * 2] + h1 * wcomb[(c0 + 1) * 2]
                     + h2 * wcomb[(c0 + 2) * 2] + h3 * wcomb[(c0 + 3) * 2];
            float p1 = h0 * wcomb[(c0 + 0) * 2 + 1] + h1 * wcomb[(c0 + 1) * 2 + 1]
                     + h2 * wcomb[(c0 + 2) * 2 + 1] + h3 * wcomb[(c0 + 3) * 2 + 1];
            if (q < 4) {
                float4 c4 = *(const float4*)(cond + (size_t)n * 16 + q * 4);
                int d0 = 80 + q * 4;
                p0 += c4.x * wcomb[(d0 + 0) * 2] + c4.y * wcomb[(d0 + 1) * 2]
                    + c4.z * wcomb[(d0 + 2) * 2] + c4.w * wcomb[(d0 + 3) * 2];
                p1 += c4.x * wcomb[(d0 + 0) * 2 + 1] + c4.y * wcomb[(d0 + 1) * 2 + 1]
                    + c4.z * wcomb[(d0 + 2) * 2 + 1] + c4.w * wcomb[(d0 + 3) * 2 + 1];
            }
            #pragma unroll
            for (int off = 1; off < 16; off <<= 1) {
                p0 += __shfl_xor(p0, off, 16);
                p1 += __shfl_xor(p1, off, 16);
            }
            if (q == 0 && nvalid) {
                out[(size_t)n * 2] = p0 + bfinal[0];
                out[(size_t)n * 2 + 1] = p1 + bfinal[1];
            }
        }
    }
}

static inline int gblk(long long threads) { return (int)((threads + BLK - 1) / BLK); }

extern "C" void kernel_launch(void* const* d_in, const int* in_sizes, int n_in,
                              void* d_out, int out_size, void* d_ws, size_t ws_size,
                              hipStream_t stream) {
    const float* x     = (const float*)d_in[0];
    const int*   ei    = (const int*)d_in[1];
    const int*   t     = (const int*)d_in[2];
    const float* cond  = (const float*)d_in[3];
    const float* Wl0   = (const float*)d_in[4];
    const float* bl0   = (const float*)d_in[5];
    const float* Wr0   = (const float*)d_in[6];
    const float* br0   = (const float*)d_in[7];
    const float* att0  = (const float*)d_in[8];
    const float* bias0 = (const float*)d_in[9];
    const float* Wres0 = (const float*)d_in[10];
    const float* bres0 = (const float*)d_in[11];
    const float* Wl1   = (const float*)d_in[12];
    const float* Wr1   = (const float*)d_in[13];
    const float* att1  = (const float*)d_in[14];
    const float* Wres1 = (const float*)d_in[15];
    const float* bres1 = (const float*)d_in[16];
    const float* Wt0   = (const float*)d_in[17];
    const float* bt0   = (const float*)d_in[18];
    const float* Wt1   = (const float*)d_in[19];
    const float* bt1   = (const float*)d_in[20];
    const float* Wfd   = (const float*)d_in[21];
    const float* bfd   = (const float*)d_in[22];
    const float* Wcls  = (const float*)d_in[23];
    const float* bcls  = (const float*)d_in[24];
    float* out = (float*)d_out;

    const int N   = in_sizes[0] / 16;
    const int E   = in_sizes[1] / 2;
    const int NBC = (N + CDST - 1) / CDST;   // coarse buckets
    const int NBF = (N + BDST - 1) / BDST;   // fine buckets

    float* ws = (float*)d_ws;
    size_t o = 0;
    float* xr    = ws + o; o += (size_t)N * 64;
    float* res   = ws + o; o += (size_t)N * 64;
    float* hbuf  = ws + o; o += (size_t)N * 64;
    _Float16* xlh = (_Float16*)(ws + o); o += (size_t)N * 32;  // 16B-aligned
    float* wcomb = ws + o; o += 192;
    float* bfin  = ws + o; o += 2;
    int* iws     = (int*)(ws + o);
    size_t io = 0;
    int* ccnt  = iws + io; io += NBC_MAX;
    int* cbase = iws + io; io += NBC_MAX + 1;
    int* ccur  = iws + io; io += NBC_MAX;
    int* fbeg  = iws + io; io += NBF;
    int* fend  = iws + io; io += NBF;
    int* part  = iws + io; io += E;
    int* srcs  = iws + io; io += E;

    const int partBlocks = (E + CHUNK - 1) / CHUNK;

    // tiny decoder/time precompute
    k_tiny<<<1, BLK, 0, stream>>>(t, Wt0, bt0, Wt1, bt1, Wfd, bfd, Wcls, bcls, wcomb, bfin);

    // ---- radix partition by destination ----
    k_zeroc<<<gblk(NBC), BLK, 0, stream>>>(ccnt, NBC);
    k_histc<<<partBlocks, BLK, 0, stream>>>(ei, E, NBC, ccnt);
    k_scan<<<1, BLK, 0, stream>>>(ccnt, NBC, E, cbase, ccur);
    k_part<<<partBlocks, BLK, 0, stream>>>(ei, E, NBC, ccur, part);
    k_refine<<<NBC, BLK, 0, stream>>>(cbase, part, NBF, fbeg, fend, srcs);

    const long long preThreads = (long long)((N + 7) / 8) * 64;

    // ---- layer 0 ----
    k_pre0v<<<gblk(preThreads), BLK, 0, stream>>>(x, Wl0, bl0, Wr0, br0, Wres0, bres0, xlh, xr, res, N);
    k_gat3<false><<<NBF, BLK, 0, stream>>>(fbeg, fend, srcs, xlh, xr, att0, bias0, res,
                                           hbuf, nullptr, nullptr, nullptr, nullptr, N);

    // ---- layer 1 (decoder fused) ----
    k_pre1v<<<gblk(preThreads), BLK, 0, stream>>>(hbuf, Wl1, Wr1, Wres1, bres1, xlh, xr, res, N);
    k_gat3<true><<<NBF, BLK, 0, stream>>>(fbeg, fend, srcs, xlh, xr, att1, nullptr, res,
                                          nullptr, cond, wcomb, bfin, out, N);
}

// Round 7
// 377.345 us; speedup vs baseline: 1.4657x; 1.0264x over previous
//
#include <hip/hip_runtime.h>
#include <hip/hip_bf16.h>
#include <hip/hip_fp16.h>
#include <math.h>

// Edge_Encoder_Residual: 2-layer GATv2 on line-graph + time-MLP + decoder.
// Round 7: k_pre1w — layer-1 node precompute with block-level LDS staging.
//   W (3x64x64) staged ONCE per block as fp16 in LDS (24KB) — was 48KB of
//   L2-streamed f32 per WAVE (600MB aggregate, the 88us stall source).
//   h rows (32 nodes, 8KB f32) staged in LDS; broadcast via same-address
//   ds_read_b128 (replaces 512 ds_bpermute/thread with 128 reads).
// Rest identical to round 6 (radix partition + gat3 + fused decoder).

#define BLK 256
#define BDST 32            // dsts per fine bucket
#define CDST 256           // dsts per coarse bucket
#define CHUNK 4096         // edges per k_part block
#define FCAP 768           // LDS tag capacity per fine bucket (mean 512)
#define NBC_MAX 512        // max coarse buckets

typedef _Float16 half4v __attribute__((ext_vector_type(4)));
typedef _Float16 half2v __attribute__((ext_vector_type(2)));

__device__ __forceinline__ float leaky02(float x) { return x >= 0.f ? x : 0.2f * x; }
__device__ __forceinline__ float relu(float x) { return x > 0.f ? x : 0.f; }

// ---------- tiny: time embedding + MLP + collapsed decoder matrices ----------
__global__ void k_tiny(const int* __restrict__ t,
                       const float* __restrict__ Wt0, const float* __restrict__ bt0,
                       const float* __restrict__ Wt1, const float* __restrict__ bt1,
                       const float* __restrict__ Wfd, const float* __restrict__ bfd,
                       const float* __restrict__ Wcls, const float* __restrict__ bcls,
                       float* __restrict__ wcomb,   // [96][2]
                       float* __restrict__ bfinal)  // [2]
{
    __shared__ float temb[16];
    int tid = threadIdx.x;
    if (tid == 0) {
        float tf = (float)t[0];
        float e0[16], v1[16];
        const float cexp = -logf(10000.f) / 7.f;
        for (int j = 0; j < 8; ++j) {
            float ang = tf * expf((float)j * cexp);
            e0[j] = sinf(ang);
            e0[8 + j] = cosf(ang);
        }
        for (int i = 0; i < 16; ++i) {
            float a = bt0[i];
            for (int j = 0; j < 16; ++j) a += e0[j] * Wt0[j * 16 + i];
            v1[i] = a / (1.f + expf(-a));
        }
        for (int i = 0; i < 16; ++i) {
            float a = bt1[i];
            for (int j = 0; j < 16; ++j) a += v1[j] * Wt1[j * 16 + i];
            temb[i] = a / (1.f + expf(-a));
        }
    }
    __syncthreads();
    if (tid < 192) {
        int i = tid >> 1, k = tid & 1;
        float a = 0.f;
        for (int j = 0; j < 32; ++j) a += Wfd[i * 32 + j] * Wcls[j * 2 + k];
        wcomb[tid] = a;
    }
    __syncthreads();
    if (tid < 2) {
        float a = bcls[tid];
        for (int j = 0; j < 32; ++j) a += bfd[j] * Wcls[j * 2 + tid];
        for (int d = 0; d < 16; ++d) a += temb[d] * wcomb[(64 + d) * 2 + tid];
        bfinal[tid] = a;
    }
}

// ---------- radix pipeline ----------
__global__ void k_zeroc(int* __restrict__ ccnt, int NBC)
{
    int gid = blockIdx.x * BLK + threadIdx.x;
    if (gid < NBC) ccnt[gid] = 0;
}

__global__ void k_histc(const int* __restrict__ ei, int E, int NBC,
                        int* __restrict__ ccnt)
{
    __shared__ int h[NBC_MAX];
    int tid = threadIdx.x;
    for (int i = tid; i < NBC; i += BLK) h[i] = 0;
    __syncthreads();
    int e0 = blockIdx.x * CHUNK;
    #pragma unroll
    for (int k = 0; k < CHUNK / BLK; ++k) {
        int e = e0 + tid + k * BLK;
        if (e < E) atomicAdd(&h[ei[E + e] >> 8], 1);
    }
    __syncthreads();
    for (int i = tid; i < NBC; i += BLK) {
        int v = h[i];
        if (v) atomicAdd(&ccnt[i], v);   // fire-and-forget -> pipelines
    }
}

__global__ void k_scan(const int* __restrict__ ccnt, int NBC, int E,
                       int* __restrict__ cbase, int* __restrict__ ccur)
{
    if (threadIdx.x == 0) {
        int acc = 0;
        for (int i = 0; i < NBC; ++i) {
            cbase[i] = acc;
            acc += ccnt[i];
        }
        cbase[NBC] = acc;
    }
    __syncthreads();
    for (int i = threadIdx.x; i < NBC; i += BLK) ccur[i] = cbase[i];
}

__global__ void k_part(const int* __restrict__ ei, int E, int NBC,
                       int* __restrict__ ccur, int* __restrict__ part)
{
    __shared__ int h[NBC_MAX];
    __shared__ int gb[NBC_MAX];
    int tid = threadIdx.x;
    int e0 = blockIdx.x * CHUNK;
    for (int i = tid; i < NBC; i += BLK) h[i] = 0;
    __syncthreads();
    int sv[CHUNK / BLK], dv[CHUNK / BLK];
    #pragma unroll
    for (int k = 0; k < CHUNK / BLK; ++k) {
        int e = e0 + tid + k * BLK;
        if (e < E) {
            sv[k] = ei[e];
            dv[k] = ei[E + e];
            atomicAdd(&h[dv[k] >> 8], 1);
        } else dv[k] = -1;
    }
    __syncthreads();
    for (int i = tid; i < NBC; i += BLK) {
        int v = h[i];
        gb[i] = v ? atomicAdd(&ccur[i], v) : 0;
    }
    __syncthreads();
    for (int i = tid; i < NBC; i += BLK) h[i] = gb[i];
    __syncthreads();
    #pragma unroll
    for (int k = 0; k < CHUNK / BLK; ++k) {
        if (dv[k] >= 0) {
            int p = atomicAdd(&h[dv[k] >> 8], 1);
            part[p] = (sv[k] << 8) | (dv[k] & 255);
        }
    }
}

__global__ void k_refine(const int* __restrict__ cbase, const int* __restrict__ part,
                         int NBF, int* __restrict__ fbeg, int* __restrict__ fend,
                         int* __restrict__ srcs)
{
    __shared__ int fcnt[8];
    __shared__ int fcur[8];
    int b = blockIdx.x, tid = threadIdx.x;
    int beg = cbase[b], end = cbase[b + 1];
    if (tid < 8) fcnt[tid] = 0;
    __syncthreads();
    for (int k = beg + tid; k < end; k += BLK)
        atomicAdd(&fcnt[(part[k] >> 5) & 7], 1);
    __syncthreads();
    if (tid == 0) {
        int acc = beg;
        #pragma unroll
        for (int f = 0; f < 8; ++f) {
            int fb = b * 8 + f;
            fcur[f] = acc;
            if (fb < NBF) { fbeg[fb] = acc; acc += fcnt[f]; fend[fb] = acc; }
        }
    }
    __syncthreads();
    for (int k = beg + tid; k < end; k += BLK) {
        int tg = part[k];
        int p = atomicAdd(&fcur[(tg >> 5) & 7], 1);
        srcs[p] = ((tg >> 8) << 5) | (tg & 31);
    }
}

// ---------- layer 0 node precompute: 8 nodes per wave, lane = channel ----------
// W tables are 16x64x3 = 12KB -> L1-resident; shfl broadcast is fine here.
__global__ void k_pre0v(const float* __restrict__ x,
                        const float* __restrict__ Wl, const float* __restrict__ bl,
                        const float* __restrict__ Wr, const float* __restrict__ br,
                        const float* __restrict__ Wres, const float* __restrict__ bres,
                        _Float16* __restrict__ xlh, float* __restrict__ xr, float* __restrict__ res,
                        int N)
{
    int wid = (int)(((long long)blockIdx.x * BLK + threadIdx.x) >> 6);
    int c = threadIdx.x & 63;
    int n0 = wid * 8;
    if (n0 >= N) return;
    int ra_n = n0 + (c >> 4);     if (ra_n >= N) ra_n = N - 1;
    int rb_n = n0 + 4 + (c >> 4); if (rb_n >= N) rb_n = N - 1;
    float ra = x[(size_t)ra_n * 16 + (c & 15)];
    float rb = x[(size_t)rb_n * 16 + (c & 15)];

    float al[8], ar[8], as[8];
    float vbl = bl[c], vbr = br[c], vbs = bres[c];
    #pragma unroll
    for (int i = 0; i < 8; ++i) { al[i] = vbl; ar[i] = vbr; as[i] = vbs; }
    #pragma unroll
    for (int k = 0; k < 16; ++k) {
        float wl = Wl[k * 64 + c], wr_ = Wr[k * 64 + c], ws = Wres[k * 64 + c];
        #pragma unroll
        for (int i = 0; i < 8; ++i) {
            float hv = __shfl(i < 4 ? ra : rb, ((i & 3) << 4) | k, 64);
            al[i] = fmaf(hv, wl, al[i]);
            ar[i] = fmaf(hv, wr_, ar[i]);
            as[i] = fmaf(hv, ws, as[i]);
        }
    }
    #pragma unroll
    for (int i = 0; i < 8; ++i) {
        int n = n0 + i;
        if (n < N) {
            xlh[(size_t)n * 64 + c] = (_Float16)al[i];
            xr[(size_t)n * 64 + c]  = ar[i];
            res[(size_t)n * 64 + c] = relu(as[i]);
        }
    }
}

// ---------- layer 1 node precompute: LDS-staged fp16 W + LDS h broadcast ------
// Block = 256 thr = 4 waves; handles 32 nodes. LDS: W 24KB + h 8KB = 32KB.
// Lane c = output channel. Wave w computes nodes w*8..w*8+7.
// wlds[k>>1][m][c][k&1]: half2 read yields W[k],W[k+1] for channel c, matrix m.
__global__ void k_pre1w(const float* __restrict__ h,
                        const float* __restrict__ Wl, const float* __restrict__ Wr,
                        const float* __restrict__ Wres, const float* __restrict__ bres,
                        _Float16* __restrict__ xlh, float* __restrict__ xr, float* __restrict__ res,
                        int N)
{
    __shared__ _Float16 wlds[32][3][64][2];
    __shared__ float hlds[32][64];
    int tid = threadIdx.x;
    int nb = blockIdx.x * 32;

    // stage W as fp16 (3*64*64 = 12288 elems, 48 per thread)
    for (int idx = tid; idx < 3 * 4096; idx += BLK) {
        int m = idx >> 12, rem = idx & 4095;
        int k = rem >> 6, c = rem & 63;
        const float* W = (m == 0) ? Wl : (m == 1) ? Wr : Wres;
        wlds[k >> 1][m][c][k & 1] = (_Float16)W[k * 64 + c];
    }
    // stage 32 h rows (clamped; writes guarded later)
    for (int idx = tid; idx < 32 * 64; idx += BLK) {
        int i = idx >> 6, c = idx & 63;
        int n = nb + i; if (n >= N) n = N - 1;
        hlds[i][c] = h[(size_t)n * 64 + c];
    }
    __syncthreads();

    int c = tid & 63, w = tid >> 6;
    float al[8], ar[8], as[8];
    float vbs = bres[c];
    #pragma unroll
    for (int i = 0; i < 8; ++i) { al[i] = 0.f; ar[i] = 0.f; as[i] = vbs; }

    #pragma unroll 4
    for (int k4 = 0; k4 < 16; ++k4) {   // k = 4*k4 .. 4*k4+3
        half2v wlA = *(const half2v*)&wlds[2 * k4][0][c][0];
        half2v wrA = *(const half2v*)&wlds[2 * k4][1][c][0];
        half2v wsA = *(const half2v*)&wlds[2 * k4][2][c][0];
        half2v wlB = *(const half2v*)&wlds[2 * k4 + 1][0][c][0];
        half2v wrB = *(const half2v*)&wlds[2 * k4 + 1][1][c][0];
        half2v wsB = *(const half2v*)&wlds[2 * k4 + 1][2][c][0];
        float l0 = (float)wlA.x, l1 = (float)wlA.y, l2 = (float)wlB.x, l3 = (float)wlB.y;
        float r0 = (float)wrA.x, r1 = (float)wrA.y, r2 = (float)wrB.x, r3 = (float)wrB.y;
        float s0 = (float)wsA.x, s1 = (float)wsA.y, s2 = (float)wsB.x, s3 = (float)wsB.y;
        #pragma unroll
        for (int i = 0; i < 8; ++i) {
            float4 hv = *(const float4*)&hlds[w * 8 + i][4 * k4];   // broadcast
            al[i] += hv.x * l0 + hv.y * l1 + hv.z * l2 + hv.w * l3;
            ar[i] += hv.x * r0 + hv.y * r1 + hv.z * r2 + hv.w * r3;
            as[i] += hv.x * s0 + hv.y * s1 + hv.z * s2 + hv.w * s3;
        }
    }
    #pragma unroll
    for (int i = 0; i < 8; ++i) {
        int n = nb + w * 8 + i;
        if (n < N) {
            xlh[(size_t)n * 64 + c] = (_Float16)al[i];
            xr[(size_t)n * 64 + c]  = ar[i];
            res[(size_t)n * 64 + c] = relu(as[i]);
        }
    }
}

// ---------- fused GATv2: one 256-thr block (4 waves) per 32-dst fine bucket ----
template <bool DEC>
__global__ void k_gat3(const int* __restrict__ fbeg, const int* __restrict__ fend,
                       const int* __restrict__ srcs,
                       const _Float16* __restrict__ xlh, const float* __restrict__ xr,
                       const float* __restrict__ att, const float* __restrict__ bias,
                       const float* __restrict__ res,
                       float* __restrict__ hout,
                       const float* __restrict__ cond, const float* __restrict__ wcomb,
                       const float* __restrict__ bfinal, float* __restrict__ out,
                       int N)
{
    __shared__ int lh[BDST];
    __shared__ int rp[BDST + 1];
    __shared__ int cc[BDST];
    __shared__ int tags[FCAP];

    int b = blockIdx.x;
    int tid = threadIdx.x;
    int beg = fbeg[b];
    int nE = fend[b] - beg; if (nE > FCAP) nE = FCAP;

    if (tid < BDST) lh[tid] = 0;
    __syncthreads();
    for (int k = tid; k < nE; k += BLK) atomicAdd(&lh[srcs[beg + k] & 31], 1);
    __syncthreads();
    if (tid == 0) {
        int acc = 0;
        rp[0] = 0;
        #pragma unroll
        for (int i = 0; i < BDST; ++i) { acc += lh[i]; rp[i + 1] = acc; }
    }
    __syncthreads();
    if (tid < BDST) cc[tid] = rp[tid];
    __syncthreads();
    for (int k = tid; k < nE; k += BLK) {
        int tg = srcs[beg + k];
        int r = atomicAdd(&cc[tg & 31], 1);
        tags[r] = tg >> 5;
    }
    __syncthreads();

    int lane = tid & 63, w = tid >> 6;
    int g = lane >> 4, q = lane & 15;
    float4 a4 = *(const float4*)(att + q * 4);

    #pragma unroll
    for (int rep = 0; rep < 2; ++rep) {
        int dlow = w * 8 + rep * 4 + g;
        int node = b * BDST + dlow;
        bool nvalid = node < N;
        int n = nvalid ? node : 0;

        float4 xr4 = *(const float4*)(xr + (size_t)n * 64 + q * 4);
        half4v hs = *(const half4v*)(xlh + (size_t)n * 64 + q * 4);
        float s0 = (float)hs.x, s1 = (float)hs.y, s2 = (float)hs.z, s3 = (float)hs.w;
        float lv = leaky02(s0 + xr4.x) * a4.x + leaky02(s1 + xr4.y) * a4.y
                 + leaky02(s2 + xr4.z) * a4.z + leaky02(s3 + xr4.w) * a4.w;
        lv += __shfl_xor(lv, 1, 8);
        lv += __shfl_xor(lv, 2, 8);
        lv += __shfl_xor(lv, 4, 8);

        float m = lv, den = 1.f;
        float ac0 = s0, ac1 = s1, ac2 = s2, ac3 = s3;

        int deg = nvalid ? (rp[dlow + 1] - rp[dlow]) : 0;
        int base = nvalid ? rp[dlow] : 0;

        int t1 = max(deg, __shfl_xor(deg, 16, 64));
        int wavemax = max(t1, __shfl_xor(t1, 32, 64));

        int s_nxt = (deg > 0) ? tags[base] : n;
        half4v h_nxt = *(const half4v*)(xlh + (size_t)s_nxt * 64 + q * 4);

        for (int j = 0; j < wavemax; ++j) {
            bool act = j < deg;
            half4v hx = h_nxt;
            int nxt = (j + 1 < deg) ? tags[base + j + 1] : n;
            h_nxt = *(const half4v*)(xlh + (size_t)nxt * 64 + q * 4);

            float x0 = (float)hx.x, x1 = (float)hx.y, x2 = (float)hx.z, x3 = (float)hx.w;
            float e = leaky02(x0 + xr4.x) * a4.x + leaky02(x1 + xr4.y) * a4.y
                    + leaky02(x2 + xr4.z) * a4.z + leaky02(x3 + xr4.w) * a4.w;
            e += __shfl_xor(e, 1, 8);
            e += __shfl_xor(e, 2, 8);
            e += __shfl_xor(e, 4, 8);
            if (!act) e = -1e30f;
            float mn = fmaxf(m, e);
            float sc = __expf(m - mn);
            float ex = __expf(e - mn);
            den = den * sc + ex;
            ac0 = ac0 * sc + ex * x0;
            ac1 = ac1 * sc + ex * x1;
            ac2 = ac2 * sc + ex * x2;
            ac3 = ac3 * sc + ex * x3;
            m = mn;
        }

        float inv = 1.f / den;
        float4 r4 = *(const float4*)(res + (size_t)n * 64 + q * 4);
        float h0, h1, h2, h3;
        if (bias) {
            const float4 b4 = *(const float4*)(bias + q * 4);
            h0 = relu(ac0 * inv + b4.x) + r4.x;
            h1 = relu(ac1 * inv + b4.y) + r4.y;
            h2 = relu(ac2 * inv + b4.z) + r4.z;
            h3 = relu(ac3 * inv + b4.w) + r4.w;
        } else {
            h0 = relu(ac0 * inv) + r4.x;
            h1 = relu(ac1 * inv) + r4.y;
            h2 = relu(ac2 * inv) + r4.z;
            h3 = relu(ac3 * inv) + r4.w;
        }

        if (!DEC) {
            if (nvalid) {
                float4 o; o.x = h0; o.y = h1; o.z = h2; o.w = h3;
                *(float4*)(hout + (size_t)n * 64 + q * 4) = o;
            }
        } else {
            int c0 = q * 4;
            float p0 = h0 * wcomb[(c0 + 0) * 2] + h1 * wcomb[(c0 + 1) * 2]
                     + h2 * wcomb[(c0 + 2) * 2] + h3 * wcomb[(c0 + 3) * 2];
            float p1 = h0 * wcomb[(c0 + 0) * 2 + 1] + h1 * wcomb[(c0 + 1) * 2 + 1]
                     + h2 * wcomb[(c0 + 2) * 2 + 1] + h3 * wcomb[(c0 + 3) * 2 + 1];
            if (q < 4) {
                float4 c4 = *(const float4*)(cond + (size_t)n * 16 + q * 4);
                int d0 = 80 + q * 4;
                p0 += c4.x * wcomb[(d0 + 0) * 2] + c4.y * wcomb[(d0 + 1) * 2]
                    + c4.z * wcomb[(d0 + 2) * 2] + c4.w * wcomb[(d0 + 3) * 2];
                p1 += c4.x * wcomb[(d0 + 0) * 2 + 1] + c4.y * wcomb[(d0 + 1) * 2 + 1]
                    + c4.z * wcomb[(d0 + 2) * 2 + 1] + c4.w * wcomb[(d0 + 3) * 2 + 1];
            }
            #pragma unroll
            for (int off = 1; off < 16; off <<= 1) {
                p0 += __shfl_xor(p0, off, 16);
                p1 += __shfl_xor(p1, off, 16);
            }
            if (q == 0 && nvalid) {
                out[(size_t)n * 2] = p0 + bfinal[0];
                out[(size_t)n * 2 + 1] = p1 + bfinal[1];
            }
        }
    }
}

static inline int gblk(long long threads) { return (int)((threads + BLK - 1) / BLK); }

extern "C" void kernel_launch(void* const* d_in, const int* in_sizes, int n_in,
                              void* d_out, int out_size, void* d_ws, size_t ws_size,
                              hipStream_t stream) {
    const float* x     = (const float*)d_in[0];
    const int*   ei    = (const int*)d_in[1];
    const int*   t     = (const int*)d_in[2];
    const float* cond  = (const float*)d_in[3];
    const float* Wl0   = (const float*)d_in[4];
    const float* bl0   = (const float*)d_in[5];
    const float* Wr0   = (const float*)d_in[6];
    const float* br0   = (const float*)d_in[7];
    const float* att0  = (const float*)d_in[8];
    const float* bias0 = (const float*)d_in[9];
    const float* Wres0 = (const float*)d_in[10];
    const float* bres0 = (const float*)d_in[11];
    const float* Wl1   = (const float*)d_in[12];
    const float* Wr1   = (const float*)d_in[13];
    const float* att1  = (const float*)d_in[14];
    const float* Wres1 = (const float*)d_in[15];
    const float* bres1 = (const float*)d_in[16];
    const float* Wt0   = (const float*)d_in[17];
    const float* bt0   = (const float*)d_in[18];
    const float* Wt1   = (const float*)d_in[19];
    const float* bt1   = (const float*)d_in[20];
    const float* Wfd   = (const float*)d_in[21];
    const float* bfd   = (const float*)d_in[22];
    const float* Wcls  = (const float*)d_in[23];
    const float* bcls  = (const float*)d_in[24];
    float* out = (float*)d_out;

    const int N   = in_sizes[0] / 16;
    const int E   = in_sizes[1] / 2;
    const int NBC = (N + CDST - 1) / CDST;   // coarse buckets
    const int NBF = (N + BDST - 1) / BDST;   // fine buckets

    float* ws = (float*)d_ws;
    size_t o = 0;
    float* xr    = ws + o; o += (size_t)N * 64;
    float* res   = ws + o; o += (size_t)N * 64;
    float* hbuf  = ws + o; o += (size_t)N * 64;
    _Float16* xlh = (_Float16*)(ws + o); o += (size_t)N * 32;  // 16B-aligned
    float* wcomb = ws + o; o += 192;
    float* bfin  = ws + o; o += 2;
    int* iws     = (int*)(ws + o);
    size_t io = 0;
    int* ccnt  = iws + io; io += NBC_MAX;
    int* cbase = iws + io; io += NBC_MAX + 1;
    int* ccur  = iws + io; io += NBC_MAX;
    int* fbeg  = iws + io; io += NBF;
    int* fend  = iws + io; io += NBF;
    int* part  = iws + io; io += E;
    int* srcs  = iws + io; io += E;

    const int partBlocks = (E + CHUNK - 1) / CHUNK;

    // tiny decoder/time precompute
    k_tiny<<<1, BLK, 0, stream>>>(t, Wt0, bt0, Wt1, bt1, Wfd, bfd, Wcls, bcls, wcomb, bfin);

    // ---- radix partition by destination ----
    k_zeroc<<<gblk(NBC), BLK, 0, stream>>>(ccnt, NBC);
    k_histc<<<partBlocks, BLK, 0, stream>>>(ei, E, NBC, ccnt);
    k_scan<<<1, BLK, 0, stream>>>(ccnt, NBC, E, cbase, ccur);
    k_part<<<partBlocks, BLK, 0, stream>>>(ei, E, NBC, ccur, part);
    k_refine<<<NBC, BLK, 0, stream>>>(cbase, part, NBF, fbeg, fend, srcs);

    const long long preThreads = (long long)((N + 7) / 8) * 64;
    const int pre1Blocks = (N + 31) / 32;

    // ---- layer 0 ----
    k_pre0v<<<gblk(preThreads), BLK, 0, stream>>>(x, Wl0, bl0, Wr0, br0, Wres0, bres0, xlh, xr, res, N);
    k_gat3<false><<<NBF, BLK, 0, stream>>>(fbeg, fend, srcs, xlh, xr, att0, bias0, res,
                                           hbuf, nullptr, nullptr, nullptr, nullptr, N);

    // ---- layer 1 (decoder fused) ----
    k_pre1w<<<pre1Blocks, BLK, 0, stream>>>(hbuf, Wl1, Wr1, Wres1, bres1, xlh, xr, res, N);
    k_gat3<true><<<NBF, BLK, 0, stream>>>(fbeg, fend, srcs, xlh, xr, att1, nullptr, res,
                                          nullptr, cond, wcomb, bfin, out, N);
}